// Round 8
// baseline (187.651 us; speedup 1.0000x reference)
//
#include <hip/hip_runtime.h>
#include <hip/hip_bf16.h>

#define D_MODEL 1024
#define NHEAD   16
#define HDIM    64
#define SEQQ    2048
#define NBATCH  2
#define MROWS   (NBATCH * SEQQ)   // 4096

typedef unsigned short u16;
typedef __attribute__((ext_vector_type(8))) short short8;   // 8 bf16 (4 VGPRs)
typedef __attribute__((ext_vector_type(4))) short bf16x4;   // 4 bf16 (2 VGPRs)
typedef __attribute__((ext_vector_type(4))) float floatx4;  // 4 fp32 acc

__device__ __forceinline__ u16 f2b(float f) {
    union { __hip_bfloat16 h; u16 u; } cv;
    cv.h = __float2bfloat16(f);
    return cv.u;
}
__device__ __forceinline__ float b2f(u16 u) {
    return __uint_as_float(((unsigned int)u) << 16);
}
__device__ __forceinline__ short8 load8(const u16* p) {
    return *reinterpret_cast<const short8*>(p);
}
__device__ __forceinline__ bf16x4 load4v(const u16* p) {
    return *reinterpret_cast<const bf16x4*>(p);
}
__device__ __forceinline__ unsigned pack2(float lo, float hi) {
    return ((unsigned)f2b(hi) << 16) | (unsigned)f2b(lo);
}
__device__ __forceinline__ void async_cp16(const void* g, void* l) {
    __builtin_amdgcn_global_load_lds(
        (const __attribute__((address_space(1))) void*)g,
        (__attribute__((address_space(3))) void*)l, 16, 0, 0);
}

// ---------------- fp32 -> bf16 convert + RoPE cos/sin table, one dispatch ----------------
// z 0..3: X quarters (flat). z 4..5: Wq/Wk with per-head row DE-INTERLEAVE
// (out row position q<32 of a head holds feature 2q; position 32+q holds
// feature 2q+1) -> rope partners land in the SAME LANE, adjacent ni, in the
// gemm epilogue. z=6..7: Wv/Wo flat. z=8: rope table tab[j*SEQQ+s]=(cos,sin).
__global__ void cvt_all(const float* __restrict__ X,
                        const float* __restrict__ w0, const float* __restrict__ w1,
                        const float* __restrict__ w2, const float* __restrict__ w3,
                        const int* __restrict__ pos,
                        u16* __restrict__ xo,
                        u16* __restrict__ o0, u16* __restrict__ o1,
                        u16* __restrict__ o2, u16* __restrict__ o3,
                        float2* __restrict__ tab) {
    const int z = blockIdx.y;
    const int i = blockIdx.x * 256 + threadIdx.x;
    if (z == 8) {
        if (i < SEQQ * 32) {
            const int j = i >> 11, s = i & (SEQQ - 1);
            const float p = (float)pos[s];
            const float inv = expf(-(float)j * (9.210340371976184f / 32.0f));
            float sn, cs;
            sincosf(p * inv, &sn, &cs);
            tab[i] = make_float2(cs, sn);
        }
        return;
    }
    const int n4 = (D_MODEL * D_MODEL) / 4;
    const float* in;
    u16* out;
    if (z < 4) { in = X + (size_t)z * n4 * 4;  out = xo + (size_t)z * n4 * 4; }
    else {
        in  = (z == 4) ? w0 : (z == 5) ? w1 : (z == 6) ? w2 : w3;
        out = (z == 4) ? o0 : (z == 5) ? o1 : (z == 6) ? o2 : o3;
    }
    int src = i;
    if (z == 4 || z == 5) {
        const int orow = i >> 8;            // out weight row (256 float4 / row)
        const int g    = i & 255;
        const int irow = (orow & ~63) | (((orow & 31) << 1) | ((orow >> 5) & 1));
        src = irow * 256 + g;
    }
    float4 v = reinterpret_cast<const float4*>(in)[src];
    ushort4 o;
    o.x = f2b(v.x); o.y = f2b(v.y); o.z = f2b(v.z); o.w = f2b(v.w);
    reinterpret_cast<ushort4*>(out)[i] = o;
}

// ---------------- QKV GEMM v4: counted-vmcnt triple-buffer + chunk swizzle ----------------
// R7 diagnosis: per-iter wall 3750 cy vs MFMA 930 / LDS 1150 / conflicts 380
// -> latency-exposed (vmcnt(0) drains DMAs issued only ~350 cy earlier).
// v4: triple buffer, prefetch distance 2: wait vmcnt(4) (stage(t) done,
// stage(t+1) in flight ACROSS the barrier), stage(t+2), compute(t). stage(t)
// gets ~2 iters (~7000 cy) to land. Buffer-safe: barrier at top of t implies
// all waves finished compute(t-1), last reader of buf (t+2)%3.
// K-chunk XOR swizzle: global source chunk c^((row>>2)&3), LDS dest linear
// (T21); reader chunk quad^(l15>>2). 8-way read conflict -> 2-way (free).
// A and B swizzled identically -> k-dim stays aligned between operands.
// Epilogue (rope fused, pipelined table loads, paired u32 stores) unchanged.
__global__ __launch_bounds__(256) void gemm_qkv(
    const u16* __restrict__ A,
    const u16* __restrict__ B0, const u16* __restrict__ B1, const u16* __restrict__ B2,
    u16* __restrict__ Qt, u16* __restrict__ Kt, u16* __restrict__ Vt,
    const float2* __restrict__ tab)
{
    const int K = D_MODEL;
    const int z = blockIdx.z;
    const u16* Bt = (z == 0) ? B0 : (z == 1 ? B1 : B2);

    __shared__ __attribute__((aligned(16))) u16 As[3][128 * 32];
    __shared__ __attribute__((aligned(16))) u16 Bs[3][128 * 32];

    const int tid  = threadIdx.x;
    const int w    = tid >> 6;
    const int lane = tid & 63;
    const int l15  = lane & 15;
    const int quad = lane >> 4;
    const int wm   = w >> 1, wn = w & 1;
    const int tm   = blockIdx.x * 128, tn = blockIdx.y * 128;

    floatx4 acc[4][4];
#pragma unroll
    for (int i = 0; i < 4; i++)
#pragma unroll
        for (int j = 0; j < 4; j++) {
            floatx4 zz = {0.f, 0.f, 0.f, 0.f};
            acc[i][j] = zz;
        }

    const int srow = lane >> 2;                               // 0..15
    const int scol = (((lane & 3) ^ ((lane >> 4) & 3))) * 8;  // swizzled chunk

    auto stage = [&](int buf, int k0) {
#pragma unroll
        for (int ch = w; ch < 8; ch += 4) {
            async_cp16(A  + (size_t)(tm + ch * 16 + srow) * K + k0 + scol, &As[buf][ch * 512]);
            async_cp16(Bt + (size_t)(tn + ch * 16 + srow) * K + k0 + scol, &Bs[buf][ch * 512]);
        }
    };

    stage(0, 0);
    stage(1, 32);

    const int rchunk = (quad ^ (l15 >> 2)) * 8;   // de-swizzling read chunk

    for (int kt = 0; kt < 32; ++kt) {
        if (kt < 30) asm volatile("s_waitcnt vmcnt(4)" ::: "memory");
        else         asm volatile("s_waitcnt vmcnt(0)" ::: "memory");
        __builtin_amdgcn_s_barrier();
        if (kt < 30) stage((kt + 2) % 3, (kt + 2) * 32);

        const u16* AsB = &As[kt % 3][0];
        const u16* BsB = &Bs[kt % 3][0];

        short8 af[4], bfr[4];
#pragma unroll
        for (int mi = 0; mi < 4; mi++)
            af[mi] = load8(&AsB[(wm * 64 + mi * 16 + l15) * 32 + rchunk]);
#pragma unroll
        for (int ni = 0; ni < 4; ni++)
            bfr[ni] = load8(&BsB[(wn * 64 + ni * 16 + l15) * 32 + rchunk]);
#pragma unroll
        for (int mi = 0; mi < 4; mi++)
#pragma unroll
            for (int ni = 0; ni < 4; ni++)
                acc[mi][ni] = __builtin_amdgcn_mfma_f32_16x16x32_bf16(af[mi], bfr[ni], acc[mi][ni], 0, 0, 0);
    }

    if (z == 2) {
        // V: write transposed [b,h,d,s]; 4 rg = 4 consecutive s, one 8B store
#pragma unroll
        for (int mi = 0; mi < 4; mi++) {
            const int r0 = tm + wm * 64 + mi * 16 + quad * 4;
            const int bb = r0 >> 11, s0 = r0 & (SEQQ - 1);
#pragma unroll
            for (int ni = 0; ni < 4; ni++) {
                const int colb = tn + wn * 64 + ni * 16 + l15;
                const int d = colb & 63, hh = colb >> 6;
                ushort4 pk;
                pk.x = f2b(acc[mi][ni][0]);
                pk.y = f2b(acc[mi][ni][1]);
                pk.z = f2b(acc[mi][ni][2]);
                pk.w = f2b(acc[mi][ni][3]);
                *reinterpret_cast<ushort4*>(
                    &Vt[(((size_t)(bb * NHEAD + hh)) * HDIM + d) * SEQQ + s0]) = pk;
            }
        }
    } else {
        // Q/K rope epilogue: pipelined table loads, paired u32 stores.
        const float qsc = (z == 0) ? 0.18033688011112042f : 1.0f;  // 0.125*log2(e) | 1
        u16* Outp = (z == 0) ? Qt : Kt;
        const int hh = (tn >> 6) + wn;      // head index, constant per thread
        float4 ta[2], tb[2];
        auto ldtab = [&](int g) {
            const int mi = g >> 1, ni = g & 1;
            const int qq = ni * 16 + l15;
            const int s0 = (tm + wm * 64 + mi * 16 + quad * 4) & (SEQQ - 1);
            ta[g & 1] = *reinterpret_cast<const float4*>(&tab[qq * SEQQ + s0]);
            tb[g & 1] = *reinterpret_cast<const float4*>(&tab[qq * SEQQ + s0 + 2]);
        };
        ldtab(0);
#pragma unroll
        for (int g = 0; g < 8; ++g) {
            if (g < 7) ldtab(g + 1);        // issue next group's loads early
            const int mi = g >> 1, ni = g & 1;
            const int qq = ni * 16 + l15;
            const int r0 = tm + wm * 64 + mi * 16 + quad * 4;
            const int bb = r0 >> 11, s0 = r0 & (SEQQ - 1);
            const float4 A4 = ta[g & 1], B4 = tb[g & 1];
            const float cs[4] = {A4.x, A4.z, B4.x, B4.z};
            const float sn[4] = {A4.y, A4.w, B4.y, B4.w};
#pragma unroll
            for (int rg = 0; rg < 4; rg++) {
                const float e = acc[mi][ni][rg];
                const float o = acc[mi][ni + 2][rg];
                const unsigned val =
                    (unsigned)f2b((e * cs[rg] - o * sn[rg]) * qsc) |
                    ((unsigned)f2b((e * sn[rg] + o * cs[rg]) * qsc) << 16);
                *reinterpret_cast<unsigned*>(
                    &Outp[(((size_t)(bb * NHEAD + hh)) * SEQQ + (s0 + rg)) * HDIM + 2 * qq]) = val;
            }
        }
    }
}

// ---------------- causal flash attention v13 (unchanged from R7) ----------------
__global__ __launch_bounds__(256, 4) void attn_kernel(
    const u16* __restrict__ Qt, const u16* __restrict__ Kt, const u16* __restrict__ Vt,
    u16* __restrict__ Out)
{
    const int bid = blockIdx.x;
    const int xcd = bid & 7;
    const int u   = bid >> 3;               // 0..127 within XCD
    const int col = xcd * 4 + (u & 3);      // (b,h) column 0..31, 4 per XCD
    const int m   = u >> 2;                 // 0..31
    int qsub;
    if      (m < 8)  qsub = 31 - m;
    else if (m < 16) qsub = m - 8;
    else if (m < 24) qsub = 39 - m;
    else             qsub = m - 16;
    const int h = col & (NHEAD - 1), b = col >> 4;

    const int tid = threadIdx.x, w = tid >> 6, lane = tid & 63;
    const int l15 = lane & 15, quad = lane >> 4;
    const size_t bh = (size_t)(b * NHEAD + h);
    const u16* Qh = Qt + bh * SEQQ * HDIM;
    const u16* Kh = Kt + bh * SEQQ * HDIM;
    const u16* Vh = Vt + bh * HDIM * SEQQ;   // [d][s]

    __shared__ __attribute__((aligned(16))) u16 Ks[2][64 * 64];   // 16 KB
    __shared__ __attribute__((aligned(16))) u16 Vs[2][64 * 64];   // 16 KB

    short8 ones;
#pragma unroll
    for (int i = 0; i < 8; i++) ones[i] = (short)0x3F80;  // bf16 1.0

    // staging: each of 4 waves stages 2 K-chunks + 2 V-chunks (1 KB each)
    const int rr  = lane >> 3;                 // 0..7
    const int swz = ((lane & 7) ^ rr) * 8;     // XOR-swizzled col offset (u16)
    auto stage = [&](int buf, int tt) {
        const int k0s = tt * 64;
        async_cp16(Kh + (size_t)(k0s + w * 8 + rr) * HDIM + swz,       &Ks[buf][w * 512]);
        async_cp16(Kh + (size_t)(k0s + (w + 4) * 8 + rr) * HDIM + swz, &Ks[buf][(w + 4) * 512]);
        async_cp16(Vh + (size_t)(w * 8 + rr) * SEQQ + k0s + swz,       &Vs[buf][w * 512]);
        async_cp16(Vh + (size_t)((w + 4) * 8 + rr) * SEQQ + k0s + swz, &Vs[buf][(w + 4) * 512]);
    };

    const int s7  = l15 & 7;
    const int sw1 = ((quad)     ^ s7) * 8;     // K dims chunk 0..31
    const int sw2 = ((quad + 4) ^ s7) * 8;     // K dims chunk 32..63
    // V b64 element offsets for permuted PV k-slots (chunk*8 + (quad&1)*4):
    const int vo0 = (((quad >> 1)    ) ^ s7) * 8 + (quad & 1) * 4;  // keys  4*quad..
    const int vo1 = (((quad >> 1) + 2) ^ s7) * 8 + (quad & 1) * 4;  // keys 16+4*quad..
    const int vo2 = (((quad >> 1) + 4) ^ s7) * 8 + (quad & 1) * 4;  // keys 32+4*quad..
    const int vo3 = (((quad >> 1) + 6) ^ s7) * 8 + (quad & 1) * 4;  // keys 48+4*quad..

    const int q0w   = qsub * 64 + w * 16;      // this wave's 16 q-rows
    const int tmaxp = qsub;                    // diag tile, same for all 4 waves

    // Q fragment loads FIRST (drained together with stage(0) by first vmcnt(0))
    short8 qf[2];
#pragma unroll
    for (int kk = 0; kk < 2; kk++)
        qf[kk] = load8(&Qh[(size_t)(q0w + l15) * HDIM + kk * 32 + quad * 8]);

    floatx4 O[4];
    floatx4 l_acc = {0.f, 0.f, 0.f, 0.f};
#pragma unroll
    for (int c = 0; c < 4; c++) { floatx4 zz = {0.f, 0.f, 0.f, 0.f}; O[c] = zz; }

    stage(0, 0);

    for (int t = 0; t <= tmaxp; ++t) {
        // stage(t) (4 DMAs, issued one full tile-compute ago) must be complete
        asm volatile("s_waitcnt vmcnt(0)" ::: "memory");
        __builtin_amdgcn_s_barrier();
        if (t < tmaxp) stage((t + 1) & 1, t + 1);   // prefetch distance 1

        const u16* KsB = &Ks[t & 1][0];
        const u16* VsB = &Vs[t & 1][0];
        const int k0 = t * 64;

        // S^T[c]: rows = key_local (c*16 + quad*4 + r), cols = q (l15)
        floatx4 S[4];
        __builtin_amdgcn_s_setprio(1);
#pragma unroll
        for (int c = 0; c < 4; c++) {
            const int rowb = (c * 16 + l15) * 64;
            floatx4 zz = {0.f, 0.f, 0.f, 0.f};
            S[c] = __builtin_amdgcn_mfma_f32_16x16x32_bf16(load8(&KsB[rowb + sw1]), qf[0], zz,   0, 0, 0);
            S[c] = __builtin_amdgcn_mfma_f32_16x16x32_bf16(load8(&KsB[rowb + sw2]), qf[1], S[c], 0, 0, 0);
        }
        __builtin_amdgcn_s_setprio(0);

        if (t == tmaxp) {
            const int q = q0w + l15;
#pragma unroll
            for (int c = 0; c < 4; c++)
#pragma unroll
                for (int r = 0; r < 4; r++)
                    if (k0 + c * 16 + quad * 4 + r > q) S[c][r] = -1e30f;
        }

#pragma unroll
        for (int c = 0; c < 4; c++)
#pragma unroll
            for (int r = 0; r < 4; r++)
                S[c][r] = __builtin_amdgcn_exp2f(S[c][r]);

        // ---- pack P into PV A-fragments (lane-local, permuted k-slots) ----
        union { short8 v; unsigned u[4]; } pf0, pf1;
        pf0.u[0] = pack2(S[0][0], S[0][1]);
        pf0.u[1] = pack2(S[0][2], S[0][3]);
        pf0.u[2] = pack2(S[1][0], S[1][1]);
        pf0.u[3] = pack2(S[1][2], S[1][3]);
        pf1.u[0] = pack2(S[2][0], S[2][1]);
        pf1.u[1] = pack2(S[2][2], S[2][3]);
        pf1.u[2] = pack2(S[3][0], S[3][1]);
        pf1.u[3] = pack2(S[3][2], S[3][3]);

        __builtin_amdgcn_s_setprio(1);
        l_acc = __builtin_amdgcn_mfma_f32_16x16x32_bf16(pf0.v, ones, l_acc, 0, 0, 0);
        l_acc = __builtin_amdgcn_mfma_f32_16x16x32_bf16(pf1.v, ones, l_acc, 0, 0, 0);

#pragma unroll
        for (int c2 = 0; c2 < 4; c2++) {
            const int rowb = (c2 * 16 + l15) * 64;
            bf16x4 a0 = load4v(&VsB[rowb + vo0]);
            bf16x4 a1 = load4v(&VsB[rowb + vo1]);
            bf16x4 a2 = load4v(&VsB[rowb + vo2]);
            bf16x4 a3 = load4v(&VsB[rowb + vo3]);
            short8 v0 = __builtin_shufflevector(a0, a1, 0, 1, 2, 3, 4, 5, 6, 7);
            short8 v1 = __builtin_shufflevector(a2, a3, 0, 1, 2, 3, 4, 5, 6, 7);
            O[c2] = __builtin_amdgcn_mfma_f32_16x16x32_bf16(pf0.v, v0, O[c2], 0, 0, 0);
            O[c2] = __builtin_amdgcn_mfma_f32_16x16x32_bf16(pf1.v, v1, O[c2], 0, 0, 0);
        }
        __builtin_amdgcn_s_setprio(0);
    }

    float inv_l[4];
#pragma unroll
    for (int r = 0; r < 4; r++) inv_l[r] = 1.0f / l_acc[r];

#pragma unroll
    for (int c2 = 0; c2 < 4; c2++)
#pragma unroll
        for (int r = 0; r < 4; r++) {
            const int q    = q0w + quad * 4 + r;
            const int colo = h * HDIM + c2 * 16 + l15;
            Out[(size_t)(b * SEQQ + q) * D_MODEL + colo] = f2b(O[c2][r] * inv_l[r]);
        }
}

// ---------------- o-proj GEMM v2: 64x64 tile, 1024 blocks, counted-vmcnt ----------------
// 4 blocks/CU independent barrier domains; triple-buffer distance-2 prefetch,
// wait vmcnt(2) (1 A-DMA + 1 B-DMA per wave per stage); chunk swizzle as in
// gemm_qkv. Waves 2x2, each 32x32 sub-tile (acc[2][2]).
__global__ __launch_bounds__(256) void gemm_o(
    const u16* __restrict__ A, const u16* __restrict__ Bt, float* __restrict__ C)
{
    const int K = D_MODEL, N = D_MODEL;
    __shared__ __attribute__((aligned(16))) u16 As[3][64 * 32];
    __shared__ __attribute__((aligned(16))) u16 Bs[3][64 * 32];

    const int tid  = threadIdx.x;
    const int w    = tid >> 6;
    const int lane = tid & 63;
    const int l15  = lane & 15;
    const int quad = lane >> 4;
    const int wm   = w >> 1, wn = w & 1;
    const int tm   = blockIdx.x * 64, tn = blockIdx.y * 64;

    floatx4 acc[2][2];
#pragma unroll
    for (int i = 0; i < 2; i++)
#pragma unroll
        for (int j = 0; j < 2; j++) {
            floatx4 z = {0.f, 0.f, 0.f, 0.f};
            acc[i][j] = z;
        }

    const int srow = lane >> 2;
    const int scol = (((lane & 3) ^ ((lane >> 4) & 3))) * 8;  // swizzled chunk

    auto stage = [&](int buf, int k0) {
        async_cp16(A  + (size_t)(tm + w * 16 + srow) * K + k0 + scol, &As[buf][w * 512]);
        async_cp16(Bt + (size_t)(tn + w * 16 + srow) * K + k0 + scol, &Bs[buf][w * 512]);
    };

    stage(0, 0);
    stage(1, 32);

    const int rchunk = (quad ^ (l15 >> 2)) * 8;

    for (int kt = 0; kt < 32; ++kt) {
        if (kt < 30) asm volatile("s_waitcnt vmcnt(2)" ::: "memory");
        else         asm volatile("s_waitcnt vmcnt(0)" ::: "memory");
        __builtin_amdgcn_s_barrier();
        if (kt < 30) stage((kt + 2) % 3, (kt + 2) * 32);

        const u16* AsB = &As[kt % 3][0];
        const u16* BsB = &Bs[kt % 3][0];

        short8 af[2], bfr[2];
#pragma unroll
        for (int mi = 0; mi < 2; mi++)
            af[mi] = load8(&AsB[(wm * 32 + mi * 16 + l15) * 32 + rchunk]);
#pragma unroll
        for (int ni = 0; ni < 2; ni++)
            bfr[ni] = load8(&BsB[(wn * 32 + ni * 16 + l15) * 32 + rchunk]);
#pragma unroll
        for (int mi = 0; mi < 2; mi++)
#pragma unroll
            for (int ni = 0; ni < 2; ni++)
                acc[mi][ni] = __builtin_amdgcn_mfma_f32_16x16x32_bf16(af[mi], bfr[ni], acc[mi][ni], 0, 0, 0);
    }

#pragma unroll
    for (int mi = 0; mi < 2; mi++)
#pragma unroll
        for (int ni = 0; ni < 2; ni++)
#pragma unroll
            for (int rg = 0; rg < 4; rg++) {
                int row = tm + wm * 32 + mi * 16 + quad * 4 + rg;
                int col = tn + wn * 32 + ni * 16 + l15;
                C[(size_t)row * N + col] = acc[mi][ni][rg];
            }
}

// ---------------- launch ----------------
extern "C" void kernel_launch(void* const* d_in, const int* in_sizes, int n_in,
                              void* d_out, int out_size, void* d_ws, size_t ws_size,
                              hipStream_t stream)
{
    const float* X  = (const float*)d_in[0];
    const float* Wq = (const float*)d_in[1];
    const float* Wk = (const float*)d_in[2];
    const float* Wv = (const float*)d_in[3];
    const float* Wo = (const float*)d_in[4];
    const int* tpos = (const int*)d_in[5];
    float* out = (float*)d_out;
    char* ws = (char*)d_ws;

    const size_t MB = (size_t)1 << 20;
    u16*    Xb  = (u16*)(ws + 0);        // 8 MB bf16 X
    u16*    WqB = (u16*)(ws + 8 * MB);
    u16*    WkB = (u16*)(ws + 10 * MB);
    u16*    WvB = (u16*)(ws + 12 * MB);
    u16*    WoB = (u16*)(ws + 14 * MB);
    float2* tab = (float2*)(ws + 16 * MB);  // 512 KB rope table (j-major)
    u16*    Qt  = (u16*)(ws + 24 * MB);
    u16*    Kt  = (u16*)(ws + 32 * MB);
    u16*    Vt  = (u16*)(ws + 40 * MB);
    u16*   AOut = (u16*)(ws + 48 * MB);

    cvt_all<<<dim3(1024, 9), 256, 0, stream>>>(X, Wq, Wk, Wv, Wo, tpos,
                                               Xb, WqB, WkB, WvB, WoB, tab);

    gemm_qkv<<<dim3(32, 8, 3), 256, 0, stream>>>(Xb, WqB, WkB, WvB,
                                                 Qt, Kt, Vt, tab);
    attn_kernel<<<dim3(1024, 1, 1), 256, 0, stream>>>(Qt, Kt, Vt, AOut);
    gemm_o<<<dim3(64, 16), 256, 0, stream>>>(AOut, WoB, out);
}

// Round 9
// 186.130 us; speedup vs baseline: 1.0082x; 1.0082x over previous
//
#include <hip/hip_runtime.h>
#include <hip/hip_bf16.h>

#define D_MODEL 1024
#define NHEAD   16
#define HDIM    64
#define SEQQ    2048
#define NBATCH  2
#define MROWS   (NBATCH * SEQQ)   // 4096

typedef unsigned short u16;
typedef __attribute__((ext_vector_type(8))) short short8;   // 8 bf16 (4 VGPRs)
typedef __attribute__((ext_vector_type(4))) short bf16x4;   // 4 bf16 (2 VGPRs)
typedef __attribute__((ext_vector_type(4))) float floatx4;  // 4 fp32 acc

__device__ __forceinline__ u16 f2b(float f) {
    union { __hip_bfloat16 h; u16 u; } cv;
    cv.h = __float2bfloat16(f);
    return cv.u;
}
__device__ __forceinline__ float b2f(u16 u) {
    return __uint_as_float(((unsigned int)u) << 16);
}
__device__ __forceinline__ short8 load8(const u16* p) {
    return *reinterpret_cast<const short8*>(p);
}
__device__ __forceinline__ bf16x4 load4v(const u16* p) {
    return *reinterpret_cast<const bf16x4*>(p);
}
__device__ __forceinline__ unsigned pack2(float lo, float hi) {
    return ((unsigned)f2b(hi) << 16) | (unsigned)f2b(lo);
}
__device__ __forceinline__ void async_cp16(const void* g, void* l) {
    __builtin_amdgcn_global_load_lds(
        (const __attribute__((address_space(1))) void*)g,
        (__attribute__((address_space(3))) void*)l, 16, 0, 0);
}

// ---------------- fp32 -> bf16 convert + RoPE cos/sin table, one dispatch ----------------
// z 0..3: X quarters (flat). z 4..5: Wq/Wk with per-head row DE-INTERLEAVE
// (out row position q<32 of a head holds feature 2q; position 32+q holds
// feature 2q+1) -> rope partners land in the SAME LANE, adjacent ni, in the
// gemm epilogue. z=6..7: Wv/Wo flat. z=8: rope table tab[j*SEQQ+s]=(cos,sin).
__global__ void cvt_all(const float* __restrict__ X,
                        const float* __restrict__ w0, const float* __restrict__ w1,
                        const float* __restrict__ w2, const float* __restrict__ w3,
                        const int* __restrict__ pos,
                        u16* __restrict__ xo,
                        u16* __restrict__ o0, u16* __restrict__ o1,
                        u16* __restrict__ o2, u16* __restrict__ o3,
                        float2* __restrict__ tab) {
    const int z = blockIdx.y;
    const int i = blockIdx.x * 256 + threadIdx.x;
    if (z == 8) {
        if (i < SEQQ * 32) {
            const int j = i >> 11, s = i & (SEQQ - 1);
            const float p = (float)pos[s];
            const float inv = expf(-(float)j * (9.210340371976184f / 32.0f));
            float sn, cs;
            sincosf(p * inv, &sn, &cs);
            tab[i] = make_float2(cs, sn);
        }
        return;
    }
    const int n4 = (D_MODEL * D_MODEL) / 4;
    const float* in;
    u16* out;
    if (z < 4) { in = X + (size_t)z * n4 * 4;  out = xo + (size_t)z * n4 * 4; }
    else {
        in  = (z == 4) ? w0 : (z == 5) ? w1 : (z == 6) ? w2 : w3;
        out = (z == 4) ? o0 : (z == 5) ? o1 : (z == 6) ? o2 : o3;
    }
    int src = i;
    if (z == 4 || z == 5) {
        const int orow = i >> 8;            // out weight row (256 float4 / row)
        const int g    = i & 255;
        const int irow = (orow & ~63) | (((orow & 31) << 1) | ((orow >> 5) & 1));
        src = irow * 256 + g;
    }
    float4 v = reinterpret_cast<const float4*>(in)[src];
    ushort4 o;
    o.x = f2b(v.x); o.y = f2b(v.y); o.z = f2b(v.z); o.w = f2b(v.w);
    reinterpret_cast<ushort4*>(out)[i] = o;
}

// ---------------- QKV GEMM v5: 64x128 tile, 1536 blocks = 6/CU ----------------
// R8 post-mortem: counted-vmcnt and chunk-swizzle both neutral (conflicts
// bit-identical; latency already covered by the 1-iter-ahead stage). Per
// CU-iter no pipe >40% busy at 3 blocks/CU -> per-wave serial chain
// (barrier -> ds latency -> MFMA issue -> barrier) with too few waves/SIMD.
// v5 = R4's occupancy lever: 64x128 tile, grid (64,8,3) = 1536 blocks =
// 6 blocks/CU (24 KB dbuf LDS x6 = 144 KB; launch_bounds(256,6) caps VGPR
// at 85, acc = 32). Halved per-wave chain, 6 independent barrier domains.
// Schedule = R7's best (dbuf, vmcnt(0), single barrier). Fused epilogue
// unchanged (mi in {0,1}).
__global__ __launch_bounds__(256, 6) void gemm_qkv(
    const u16* __restrict__ A,
    const u16* __restrict__ B0, const u16* __restrict__ B1, const u16* __restrict__ B2,
    u16* __restrict__ Qt, u16* __restrict__ Kt, u16* __restrict__ Vt,
    const float2* __restrict__ tab)
{
    const int K = D_MODEL;
    const int z = blockIdx.z;
    const u16* Bt = (z == 0) ? B0 : (z == 1 ? B1 : B2);

    __shared__ __attribute__((aligned(16))) u16 As[2][64 * 32];    // 8 KB
    __shared__ __attribute__((aligned(16))) u16 Bs[2][128 * 32];   // 16 KB

    const int tid  = threadIdx.x;
    const int w    = tid >> 6;
    const int lane = tid & 63;
    const int l15  = lane & 15;
    const int quad = lane >> 4;
    const int wm   = w >> 1, wn = w & 1;
    const int tm   = blockIdx.x * 64, tn = blockIdx.y * 128;

    floatx4 acc[2][4];
#pragma unroll
    for (int i = 0; i < 2; i++)
#pragma unroll
        for (int j = 0; j < 4; j++) {
            floatx4 zz = {0.f, 0.f, 0.f, 0.f};
            acc[i][j] = zz;
        }

    const int srow = lane >> 2;
    const int scol = (lane & 3) * 8;

    auto stage = [&](int buf, int k0) {
#pragma unroll
        for (int ch = w; ch < 12; ch += 4) {
            if (ch < 4) async_cp16(A  + (size_t)(tm + ch * 16 + srow) * K + k0 + scol,
                                   &As[buf][ch * 512]);
            else        async_cp16(Bt + (size_t)(tn + (ch - 4) * 16 + srow) * K + k0 + scol,
                                   &Bs[buf][(ch - 4) * 512]);
        }
    };

    stage(0, 0);

    for (int kt = 0; kt < 32; ++kt) {
        asm volatile("s_waitcnt vmcnt(0)" ::: "memory");
        __builtin_amdgcn_s_barrier();
        if (kt < 31) stage((kt + 1) & 1, (kt + 1) * 32);

        const u16* AsB = &As[kt & 1][0];
        const u16* BsB = &Bs[kt & 1][0];

        short8 af[2], bfr[4];
#pragma unroll
        for (int mi = 0; mi < 2; mi++)
            af[mi] = load8(&AsB[(wm * 32 + mi * 16 + l15) * 32 + quad * 8]);
#pragma unroll
        for (int ni = 0; ni < 4; ni++)
            bfr[ni] = load8(&BsB[(wn * 64 + ni * 16 + l15) * 32 + quad * 8]);
#pragma unroll
        for (int mi = 0; mi < 2; mi++)
#pragma unroll
            for (int ni = 0; ni < 4; ni++)
                acc[mi][ni] = __builtin_amdgcn_mfma_f32_16x16x32_bf16(af[mi], bfr[ni], acc[mi][ni], 0, 0, 0);
    }

    if (z == 2) {
        // V: write transposed [b,h,d,s]; 4 rg = 4 consecutive s, one 8B store
#pragma unroll
        for (int mi = 0; mi < 2; mi++) {
            const int r0 = tm + wm * 32 + mi * 16 + quad * 4;
            const int bb = r0 >> 11, s0 = r0 & (SEQQ - 1);
#pragma unroll
            for (int ni = 0; ni < 4; ni++) {
                const int colb = tn + wn * 64 + ni * 16 + l15;
                const int d = colb & 63, hh = colb >> 6;
                ushort4 pk;
                pk.x = f2b(acc[mi][ni][0]);
                pk.y = f2b(acc[mi][ni][1]);
                pk.z = f2b(acc[mi][ni][2]);
                pk.w = f2b(acc[mi][ni][3]);
                *reinterpret_cast<ushort4*>(
                    &Vt[(((size_t)(bb * NHEAD + hh)) * HDIM + d) * SEQQ + s0]) = pk;
            }
        }
    } else {
        // Q/K rope epilogue: pipelined table loads, paired u32 stores.
        const float qsc = (z == 0) ? 0.18033688011112042f : 1.0f;  // 0.125*log2(e) | 1
        u16* Outp = (z == 0) ? Qt : Kt;
        const int hh = (tn >> 6) + wn;      // head index, constant per thread
        float4 ta[2], tb[2];
        auto ldtab = [&](int g) {
            const int mi = g >> 1, ni = g & 1;
            const int qq = ni * 16 + l15;
            const int s0 = (tm + wm * 32 + mi * 16 + quad * 4) & (SEQQ - 1);
            ta[g & 1] = *reinterpret_cast<const float4*>(&tab[qq * SEQQ + s0]);
            tb[g & 1] = *reinterpret_cast<const float4*>(&tab[qq * SEQQ + s0 + 2]);
        };
        ldtab(0);
#pragma unroll
        for (int g = 0; g < 4; ++g) {
            if (g < 3) ldtab(g + 1);        // issue next group's loads early
            const int mi = g >> 1, ni = g & 1;
            const int qq = ni * 16 + l15;
            const int r0 = tm + wm * 32 + mi * 16 + quad * 4;
            const int bb = r0 >> 11, s0 = r0 & (SEQQ - 1);
            const float4 A4 = ta[g & 1], B4 = tb[g & 1];
            const float cs[4] = {A4.x, A4.z, B4.x, B4.z};
            const float sn[4] = {A4.y, A4.w, B4.y, B4.w};
#pragma unroll
            for (int rg = 0; rg < 4; rg++) {
                const float e = acc[mi][ni][rg];
                const float o = acc[mi][ni + 2][rg];
                const unsigned val =
                    (unsigned)f2b((e * cs[rg] - o * sn[rg]) * qsc) |
                    ((unsigned)f2b((e * sn[rg] + o * cs[rg]) * qsc) << 16);
                *reinterpret_cast<unsigned*>(
                    &Outp[(((size_t)(bb * NHEAD + hh)) * SEQQ + (s0 + rg)) * HDIM + 2 * qq]) = val;
            }
        }
    }
}

// ---------------- causal flash attention v13 (unchanged) ----------------
__global__ __launch_bounds__(256, 4) void attn_kernel(
    const u16* __restrict__ Qt, const u16* __restrict__ Kt, const u16* __restrict__ Vt,
    u16* __restrict__ Out)
{
    const int bid = blockIdx.x;
    const int xcd = bid & 7;
    const int u   = bid >> 3;               // 0..127 within XCD
    const int col = xcd * 4 + (u & 3);      // (b,h) column 0..31, 4 per XCD
    const int m   = u >> 2;                 // 0..31
    int qsub;
    if      (m < 8)  qsub = 31 - m;
    else if (m < 16) qsub = m - 8;
    else if (m < 24) qsub = 39 - m;
    else             qsub = m - 16;
    const int h = col & (NHEAD - 1), b = col >> 4;

    const int tid = threadIdx.x, w = tid >> 6, lane = tid & 63;
    const int l15 = lane & 15, quad = lane >> 4;
    const size_t bh = (size_t)(b * NHEAD + h);
    const u16* Qh = Qt + bh * SEQQ * HDIM;
    const u16* Kh = Kt + bh * SEQQ * HDIM;
    const u16* Vh = Vt + bh * HDIM * SEQQ;   // [d][s]

    __shared__ __attribute__((aligned(16))) u16 Ks[2][64 * 64];   // 16 KB
    __shared__ __attribute__((aligned(16))) u16 Vs[2][64 * 64];   // 16 KB

    short8 ones;
#pragma unroll
    for (int i = 0; i < 8; i++) ones[i] = (short)0x3F80;  // bf16 1.0

    // staging: each of 4 waves stages 2 K-chunks + 2 V-chunks (1 KB each)
    const int rr  = lane >> 3;                 // 0..7
    const int swz = ((lane & 7) ^ rr) * 8;     // XOR-swizzled col offset (u16)
    auto stage = [&](int buf, int tt) {
        const int k0s = tt * 64;
        async_cp16(Kh + (size_t)(k0s + w * 8 + rr) * HDIM + swz,       &Ks[buf][w * 512]);
        async_cp16(Kh + (size_t)(k0s + (w + 4) * 8 + rr) * HDIM + swz, &Ks[buf][(w + 4) * 512]);
        async_cp16(Vh + (size_t)(w * 8 + rr) * SEQQ + k0s + swz,       &Vs[buf][w * 512]);
        async_cp16(Vh + (size_t)((w + 4) * 8 + rr) * SEQQ + k0s + swz, &Vs[buf][(w + 4) * 512]);
    };

    const int s7  = l15 & 7;
    const int sw1 = ((quad)     ^ s7) * 8;     // K dims chunk 0..31
    const int sw2 = ((quad + 4) ^ s7) * 8;     // K dims chunk 32..63
    // V b64 element offsets for permuted PV k-slots (chunk*8 + (quad&1)*4):
    const int vo0 = (((quad >> 1)    ) ^ s7) * 8 + (quad & 1) * 4;  // keys  4*quad..
    const int vo1 = (((quad >> 1) + 2) ^ s7) * 8 + (quad & 1) * 4;  // keys 16+4*quad..
    const int vo2 = (((quad >> 1) + 4) ^ s7) * 8 + (quad & 1) * 4;  // keys 32+4*quad..
    const int vo3 = (((quad >> 1) + 6) ^ s7) * 8 + (quad & 1) * 4;  // keys 48+4*quad..

    const int q0w   = qsub * 64 + w * 16;      // this wave's 16 q-rows
    const int tmaxp = qsub;                    // diag tile, same for all 4 waves

    // Q fragment loads FIRST (drained together with stage(0) by first vmcnt(0))
    short8 qf[2];
#pragma unroll
    for (int kk = 0; kk < 2; kk++)
        qf[kk] = load8(&Qh[(size_t)(q0w + l15) * HDIM + kk * 32 + quad * 8]);

    floatx4 O[4];
    floatx4 l_acc = {0.f, 0.f, 0.f, 0.f};
#pragma unroll
    for (int c = 0; c < 4; c++) { floatx4 zz = {0.f, 0.f, 0.f, 0.f}; O[c] = zz; }

    stage(0, 0);

    for (int t = 0; t <= tmaxp; ++t) {
        // stage(t) (4 DMAs, issued one full tile-compute ago) must be complete
        asm volatile("s_waitcnt vmcnt(0)" ::: "memory");
        __builtin_amdgcn_s_barrier();
        if (t < tmaxp) stage((t + 1) & 1, t + 1);   // prefetch distance 1

        const u16* KsB = &Ks[t & 1][0];
        const u16* VsB = &Vs[t & 1][0];
        const int k0 = t * 64;

        // S^T[c]: rows = key_local (c*16 + quad*4 + r), cols = q (l15)
        floatx4 S[4];
        __builtin_amdgcn_s_setprio(1);
#pragma unroll
        for (int c = 0; c < 4; c++) {
            const int rowb = (c * 16 + l15) * 64;
            floatx4 zz = {0.f, 0.f, 0.f, 0.f};
            S[c] = __builtin_amdgcn_mfma_f32_16x16x32_bf16(load8(&KsB[rowb + sw1]), qf[0], zz,   0, 0, 0);
            S[c] = __builtin_amdgcn_mfma_f32_16x16x32_bf16(load8(&KsB[rowb + sw2]), qf[1], S[c], 0, 0, 0);
        }
        __builtin_amdgcn_s_setprio(0);

        if (t == tmaxp) {
            const int q = q0w + l15;
#pragma unroll
            for (int c = 0; c < 4; c++)
#pragma unroll
                for (int r = 0; r < 4; r++)
                    if (k0 + c * 16 + quad * 4 + r > q) S[c][r] = -1e30f;
        }

#pragma unroll
        for (int c = 0; c < 4; c++)
#pragma unroll
            for (int r = 0; r < 4; r++)
                S[c][r] = __builtin_amdgcn_exp2f(S[c][r]);

        // ---- pack P into PV A-fragments (lane-local, permuted k-slots) ----
        union { short8 v; unsigned u[4]; } pf0, pf1;
        pf0.u[0] = pack2(S[0][0], S[0][1]);
        pf0.u[1] = pack2(S[0][2], S[0][3]);
        pf0.u[2] = pack2(S[1][0], S[1][1]);
        pf0.u[3] = pack2(S[1][2], S[1][3]);
        pf1.u[0] = pack2(S[2][0], S[2][1]);
        pf1.u[1] = pack2(S[2][2], S[2][3]);
        pf1.u[2] = pack2(S[3][0], S[3][1]);
        pf1.u[3] = pack2(S[3][2], S[3][3]);

        __builtin_amdgcn_s_setprio(1);
        l_acc = __builtin_amdgcn_mfma_f32_16x16x32_bf16(pf0.v, ones, l_acc, 0, 0, 0);
        l_acc = __builtin_amdgcn_mfma_f32_16x16x32_bf16(pf1.v, ones, l_acc, 0, 0, 0);

#pragma unroll
        for (int c2 = 0; c2 < 4; c2++) {
            const int rowb = (c2 * 16 + l15) * 64;
            bf16x4 a0 = load4v(&VsB[rowb + vo0]);
            bf16x4 a1 = load4v(&VsB[rowb + vo1]);
            bf16x4 a2 = load4v(&VsB[rowb + vo2]);
            bf16x4 a3 = load4v(&VsB[rowb + vo3]);
            short8 v0 = __builtin_shufflevector(a0, a1, 0, 1, 2, 3, 4, 5, 6, 7);
            short8 v1 = __builtin_shufflevector(a2, a3, 0, 1, 2, 3, 4, 5, 6, 7);
            O[c2] = __builtin_amdgcn_mfma_f32_16x16x32_bf16(pf0.v, v0, O[c2], 0, 0, 0);
            O[c2] = __builtin_amdgcn_mfma_f32_16x16x32_bf16(pf1.v, v1, O[c2], 0, 0, 0);
        }
        __builtin_amdgcn_s_setprio(0);
    }

    float inv_l[4];
#pragma unroll
    for (int r = 0; r < 4; r++) inv_l[r] = 1.0f / l_acc[r];

#pragma unroll
    for (int c2 = 0; c2 < 4; c2++)
#pragma unroll
        for (int r = 0; r < 4; r++) {
            const int q    = q0w + quad * 4 + r;
            const int colo = h * HDIM + c2 * 16 + l15;
            Out[(size_t)(b * SEQQ + q) * D_MODEL + colo] = f2b(O[c2][r] * inv_l[r]);
        }
}

// ---------------- o-proj GEMM: 64x64 tile, 1024 blocks (unchanged from R8) ----------------
__global__ __launch_bounds__(256) void gemm_o(
    const u16* __restrict__ A, const u16* __restrict__ Bt, float* __restrict__ C)
{
    const int K = D_MODEL, N = D_MODEL;
    __shared__ __attribute__((aligned(16))) u16 As[3][64 * 32];
    __shared__ __attribute__((aligned(16))) u16 Bs[3][64 * 32];

    const int tid  = threadIdx.x;
    const int w    = tid >> 6;
    const int lane = tid & 63;
    const int l15  = lane & 15;
    const int quad = lane >> 4;
    const int wm   = w >> 1, wn = w & 1;
    const int tm   = blockIdx.x * 64, tn = blockIdx.y * 64;

    floatx4 acc[2][2];
#pragma unroll
    for (int i = 0; i < 2; i++)
#pragma unroll
        for (int j = 0; j < 2; j++) {
            floatx4 z = {0.f, 0.f, 0.f, 0.f};
            acc[i][j] = z;
        }

    const int srow = lane >> 2;
    const int scol = (lane & 3) * 8;

    auto stage = [&](int buf, int k0) {
        async_cp16(A  + (size_t)(tm + w * 16 + srow) * K + k0 + scol, &As[buf][w * 512]);
        async_cp16(Bt + (size_t)(tn + w * 16 + srow) * K + k0 + scol, &Bs[buf][w * 512]);
    };

    stage(0, 0);
    stage(1, 32);

    for (int kt = 0; kt < 32; ++kt) {
        if (kt < 30) asm volatile("s_waitcnt vmcnt(2)" ::: "memory");
        else         asm volatile("s_waitcnt vmcnt(0)" ::: "memory");
        __builtin_amdgcn_s_barrier();
        if (kt < 30) stage((kt + 2) % 3, (kt + 2) * 32);

        const u16* AsB = &As[kt % 3][0];
        const u16* BsB = &Bs[kt % 3][0];

        short8 af[2], bfr[2];
#pragma unroll
        for (int mi = 0; mi < 2; mi++)
            af[mi] = load8(&AsB[(wm * 32 + mi * 16 + l15) * 32 + quad * 8]);
#pragma unroll
        for (int ni = 0; ni < 2; ni++)
            bfr[ni] = load8(&BsB[(wn * 32 + ni * 16 + l15) * 32 + quad * 8]);
#pragma unroll
        for (int mi = 0; mi < 2; mi++)
#pragma unroll
            for (int ni = 0; ni < 2; ni++)
                acc[mi][ni] = __builtin_amdgcn_mfma_f32_16x16x32_bf16(af[mi], bfr[ni], acc[mi][ni], 0, 0, 0);
    }

#pragma unroll
    for (int mi = 0; mi < 2; mi++)
#pragma unroll
        for (int ni = 0; ni < 2; ni++)
#pragma unroll
            for (int rg = 0; rg < 4; rg++) {
                int row = tm + wm * 32 + mi * 16 + quad * 4 + rg;
                int col = tn + wn * 32 + ni * 16 + l15;
                C[(size_t)row * N + col] = acc[mi][ni][rg];
            }
}

// ---------------- launch ----------------
extern "C" void kernel_launch(void* const* d_in, const int* in_sizes, int n_in,
                              void* d_out, int out_size, void* d_ws, size_t ws_size,
                              hipStream_t stream)
{
    const float* X  = (const float*)d_in[0];
    const float* Wq = (const float*)d_in[1];
    const float* Wk = (const float*)d_in[2];
    const float* Wv = (const float*)d_in[3];
    const float* Wo = (const float*)d_in[4];
    const int* tpos = (const int*)d_in[5];
    float* out = (float*)d_out;
    char* ws = (char*)d_ws;

    const size_t MB = (size_t)1 << 20;
    u16*    Xb  = (u16*)(ws + 0);        // 8 MB bf16 X
    u16*    WqB = (u16*)(ws + 8 * MB);
    u16*    WkB = (u16*)(ws + 10 * MB);
    u16*    WvB = (u16*)(ws + 12 * MB);
    u16*    WoB = (u16*)(ws + 14 * MB);
    float2* tab = (float2*)(ws + 16 * MB);  // 512 KB rope table (j-major)
    u16*    Qt  = (u16*)(ws + 24 * MB);
    u16*    Kt  = (u16*)(ws + 32 * MB);
    u16*    Vt  = (u16*)(ws + 40 * MB);
    u16*   AOut = (u16*)(ws + 48 * MB);

    cvt_all<<<dim3(1024, 9), 256, 0, stream>>>(X, Wq, Wk, Wv, Wo, tpos,
                                               Xb, WqB, WkB, WvB, WoB, tab);

    gemm_qkv<<<dim3(64, 8, 3), 256, 0, stream>>>(Xb, WqB, WkB, WvB,
                                                 Qt, Kt, Vt, tab);
    attn_kernel<<<dim3(1024, 1, 1), 256, 0, stream>>>(Qt, Kt, Vt, AOut);
    gemm_o<<<dim3(64, 16), 256, 0, stream>>>(AOut, WoB, out);
}

// Round 10
// 183.911 us; speedup vs baseline: 1.0203x; 1.0121x over previous
//
#include <hip/hip_runtime.h>
#include <hip/hip_bf16.h>

#define D_MODEL 1024
#define NHEAD   16
#define HDIM    64
#define SEQQ    2048
#define NBATCH  2
#define MROWS   (NBATCH * SEQQ)   // 4096

typedef unsigned short u16;
typedef __attribute__((ext_vector_type(8))) short short8;   // 8 bf16 (4 VGPRs)
typedef __attribute__((ext_vector_type(4))) short bf16x4;   // 4 bf16 (2 VGPRs)
typedef __attribute__((ext_vector_type(4))) float floatx4;  // 4 fp32 acc

__device__ __forceinline__ u16 f2b(float f) {
    union { __hip_bfloat16 h; u16 u; } cv;
    cv.h = __float2bfloat16(f);
    return cv.u;
}
__device__ __forceinline__ float b2f(u16 u) {
    return __uint_as_float(((unsigned int)u) << 16);
}
__device__ __forceinline__ short8 load8(const u16* p) {
    return *reinterpret_cast<const short8*>(p);
}
__device__ __forceinline__ bf16x4 load4v(const u16* p) {
    return *reinterpret_cast<const bf16x4*>(p);
}
__device__ __forceinline__ unsigned pack2(float lo, float hi) {
    return ((unsigned)f2b(hi) << 16) | (unsigned)f2b(lo);
}
__device__ __forceinline__ void async_cp16(const void* g, void* l) {
    __builtin_amdgcn_global_load_lds(
        (const __attribute__((address_space(1))) void*)g,
        (__attribute__((address_space(3))) void*)l, 16, 0, 0);
}

// ---------------- fp32 -> bf16 convert + RoPE cos/sin table, one dispatch ----------------
// z 0..3: X quarters (flat). z 4..5: Wq/Wk with per-head row DE-INTERLEAVE
// (out row position q<32 of a head holds feature 2q; position 32+q holds
// feature 2q+1) -> rope partners land in the SAME LANE, adjacent ni, in the
// gemm epilogue. z=6..7: Wv/Wo flat. z=8: rope table tab[j*SEQQ+s]=(cos,sin).
__global__ void cvt_all(const float* __restrict__ X,
                        const float* __restrict__ w0, const float* __restrict__ w1,
                        const float* __restrict__ w2, const float* __restrict__ w3,
                        const int* __restrict__ pos,
                        u16* __restrict__ xo,
                        u16* __restrict__ o0, u16* __restrict__ o1,
                        u16* __restrict__ o2, u16* __restrict__ o3,
                        float2* __restrict__ tab) {
    const int z = blockIdx.y;
    const int i = blockIdx.x * 256 + threadIdx.x;
    if (z == 8) {
        if (i < SEQQ * 32) {
            const int j = i >> 11, s = i & (SEQQ - 1);
            const float p = (float)pos[s];
            const float inv = expf(-(float)j * (9.210340371976184f / 32.0f));
            float sn, cs;
            sincosf(p * inv, &sn, &cs);
            tab[i] = make_float2(cs, sn);
        }
        return;
    }
    const int n4 = (D_MODEL * D_MODEL) / 4;
    const float* in;
    u16* out;
    if (z < 4) { in = X + (size_t)z * n4 * 4;  out = xo + (size_t)z * n4 * 4; }
    else {
        in  = (z == 4) ? w0 : (z == 5) ? w1 : (z == 6) ? w2 : w3;
        out = (z == 4) ? o0 : (z == 5) ? o1 : (z == 6) ? o2 : o3;
    }
    int src = i;
    if (z == 4 || z == 5) {
        const int orow = i >> 8;            // out weight row (256 float4 / row)
        const int g    = i & 255;
        const int irow = (orow & ~63) | (((orow & 31) << 1) | ((orow >> 5) & 1));
        src = irow * 256 + g;
    }
    float4 v = reinterpret_cast<const float4*>(in)[src];
    ushort4 o;
    o.x = f2b(v.x); o.y = f2b(v.y); o.z = f2b(v.z); o.w = f2b(v.w);
    reinterpret_cast<ushort4*>(out)[i] = o;
}

// ---------------- merged QKV GEMM v6: one block does Q,K,V for its (m,n) tile ----------------
// R9 falsified occupancy (15->44% at SAME 50us) and R8 falsified vmcnt/swizzle:
// the cost is per-K-iter structural overhead (barrier + ds latency + issue)
// amortized over only 8 MFMA/wave. v6 merges the 3 z-slices: A staged ONCE
// (A-fetch /3), each K-iter runs 24 MFMA/wave against one barrier pair (3x
// chain amortization). 64x128 tile, 2x2 waves (wave = 32 rows x 64 cols = one
// full head per wn -> rope pairing stays lane-local). LDS 8+48=56 KB dbuf ->
// 2 blocks/CU; acc 24 x floatx4 = 96 VGPR, launch_bounds(256,2), all loops
// fully unrolled (static acc indexing). Epilogues: V transpose store, Q rope,
// K rope (all as previously verified).
__global__ __launch_bounds__(256, 2) void gemm_qkv(
    const u16* __restrict__ A,
    const u16* __restrict__ B0, const u16* __restrict__ B1, const u16* __restrict__ B2,
    u16* __restrict__ Qt, u16* __restrict__ Kt, u16* __restrict__ Vt,
    const float2* __restrict__ tab)
{
    const int K = D_MODEL;

    __shared__ __attribute__((aligned(16))) u16 As[2][64 * 32];        // 8 KB
    __shared__ __attribute__((aligned(16))) u16 Bs[2][3][128 * 32];    // 48 KB

    const int tid  = threadIdx.x;
    const int w    = tid >> 6;
    const int lane = tid & 63;
    const int l15  = lane & 15;
    const int quad = lane >> 4;
    const int wm   = w >> 1, wn = w & 1;
    const int tm   = blockIdx.x * 64, tn = blockIdx.y * 128;

    floatx4 acc[3][2][4];
#pragma unroll
    for (int zz = 0; zz < 3; zz++)
#pragma unroll
        for (int i = 0; i < 2; i++)
#pragma unroll
            for (int j = 0; j < 4; j++) {
                floatx4 z4 = {0.f, 0.f, 0.f, 0.f};
                acc[zz][i][j] = z4;
            }

    const int srow = lane >> 2;
    const int scol = (lane & 3) * 8;

    // per thread per stage: 1 A-chunk + 3x2 B-chunks = 7 async_cp16
    auto stage = [&](int buf, int k0) {
        async_cp16(A + (size_t)(tm + w * 16 + srow) * K + k0 + scol, &As[buf][w * 512]);
#pragma unroll
        for (int ch = w; ch < 8; ch += 4) {
            async_cp16(B0 + (size_t)(tn + ch * 16 + srow) * K + k0 + scol, &Bs[buf][0][ch * 512]);
            async_cp16(B1 + (size_t)(tn + ch * 16 + srow) * K + k0 + scol, &Bs[buf][1][ch * 512]);
            async_cp16(B2 + (size_t)(tn + ch * 16 + srow) * K + k0 + scol, &Bs[buf][2][ch * 512]);
        }
    };

    stage(0, 0);

    for (int kt = 0; kt < 32; ++kt) {
        asm volatile("s_waitcnt vmcnt(0)" ::: "memory");
        __builtin_amdgcn_s_barrier();
        if (kt < 31) stage((kt + 1) & 1, (kt + 1) * 32);

        const int buf = kt & 1;
        short8 af[2];
#pragma unroll
        for (int mi = 0; mi < 2; mi++)
            af[mi] = load8(&As[buf][(wm * 32 + mi * 16 + l15) * 32 + quad * 8]);

#pragma unroll
        for (int zz = 0; zz < 3; zz++) {
            short8 bfr[4];
#pragma unroll
            for (int ni = 0; ni < 4; ni++)
                bfr[ni] = load8(&Bs[buf][zz][(wn * 64 + ni * 16 + l15) * 32 + quad * 8]);
#pragma unroll
            for (int mi = 0; mi < 2; mi++)
#pragma unroll
                for (int ni = 0; ni < 4; ni++)
                    acc[zz][mi][ni] = __builtin_amdgcn_mfma_f32_16x16x32_bf16(
                        af[mi], bfr[ni], acc[zz][mi][ni], 0, 0, 0);
        }
    }

    // ---- epilogue 1: V transpose store [b,h,d,s] (z=2) ----
#pragma unroll
    for (int mi = 0; mi < 2; mi++) {
        const int r0 = tm + wm * 32 + mi * 16 + quad * 4;
        const int bb = r0 >> 11, s0 = r0 & (SEQQ - 1);
#pragma unroll
        for (int ni = 0; ni < 4; ni++) {
            const int colb = tn + wn * 64 + ni * 16 + l15;
            const int d = colb & 63, hh = colb >> 6;
            ushort4 pk;
            pk.x = f2b(acc[2][mi][ni][0]);
            pk.y = f2b(acc[2][mi][ni][1]);
            pk.z = f2b(acc[2][mi][ni][2]);
            pk.w = f2b(acc[2][mi][ni][3]);
            *reinterpret_cast<ushort4*>(
                &Vt[(((size_t)(bb * NHEAD + hh)) * HDIM + d) * SEQQ + s0]) = pk;
        }
    }

    // ---- epilogue 2+3: Q and K rope (pipelined table loads, paired u32 stores) ----
    const int hh = (tn >> 6) + wn;          // head index, constant per thread
#pragma unroll
    for (int zz = 0; zz < 2; zz++) {
        const float qsc = (zz == 0) ? 0.18033688011112042f : 1.0f;  // 0.125*log2(e) | 1
        u16* Outp = (zz == 0) ? Qt : Kt;
        float4 ta[2], tb[2];
        auto ldtab = [&](int g) {
            const int mi = g >> 1, ni = g & 1;
            const int qq = ni * 16 + l15;
            const int s0 = (tm + wm * 32 + mi * 16 + quad * 4) & (SEQQ - 1);
            ta[g & 1] = *reinterpret_cast<const float4*>(&tab[qq * SEQQ + s0]);
            tb[g & 1] = *reinterpret_cast<const float4*>(&tab[qq * SEQQ + s0 + 2]);
        };
        ldtab(0);
#pragma unroll
        for (int g = 0; g < 4; ++g) {
            if (g < 3) ldtab(g + 1);        // issue next group's loads early
            const int mi = g >> 1, ni = g & 1;
            const int qq = ni * 16 + l15;
            const int r0 = tm + wm * 32 + mi * 16 + quad * 4;
            const int bb = r0 >> 11, s0 = r0 & (SEQQ - 1);
            const float4 A4 = ta[g & 1], B4 = tb[g & 1];
            const float cs[4] = {A4.x, A4.z, B4.x, B4.z};
            const float sn[4] = {A4.y, A4.w, B4.y, B4.w};
#pragma unroll
            for (int rg = 0; rg < 4; rg++) {
                const float e = acc[zz][mi][ni][rg];
                const float o = acc[zz][mi][ni + 2][rg];
                const unsigned val =
                    (unsigned)f2b((e * cs[rg] - o * sn[rg]) * qsc) |
                    ((unsigned)f2b((e * sn[rg] + o * cs[rg]) * qsc) << 16);
                *reinterpret_cast<unsigned*>(
                    &Outp[(((size_t)(bb * NHEAD + hh)) * SEQQ + (s0 + rg)) * HDIM + 2 * qq]) = val;
            }
        }
    }
}

// ---------------- causal flash attention v13 (unchanged) ----------------
__global__ __launch_bounds__(256, 4) void attn_kernel(
    const u16* __restrict__ Qt, const u16* __restrict__ Kt, const u16* __restrict__ Vt,
    u16* __restrict__ Out)
{
    const int bid = blockIdx.x;
    const int xcd = bid & 7;
    const int u   = bid >> 3;               // 0..127 within XCD
    const int col = xcd * 4 + (u & 3);      // (b,h) column 0..31, 4 per XCD
    const int m   = u >> 2;                 // 0..31
    int qsub;
    if      (m < 8)  qsub = 31 - m;
    else if (m < 16) qsub = m - 8;
    else if (m < 24) qsub = 39 - m;
    else             qsub = m - 16;
    const int h = col & (NHEAD - 1), b = col >> 4;

    const int tid = threadIdx.x, w = tid >> 6, lane = tid & 63;
    const int l15 = lane & 15, quad = lane >> 4;
    const size_t bh = (size_t)(b * NHEAD + h);
    const u16* Qh = Qt + bh * SEQQ * HDIM;
    const u16* Kh = Kt + bh * SEQQ * HDIM;
    const u16* Vh = Vt + bh * HDIM * SEQQ;   // [d][s]

    __shared__ __attribute__((aligned(16))) u16 Ks[2][64 * 64];   // 16 KB
    __shared__ __attribute__((aligned(16))) u16 Vs[2][64 * 64];   // 16 KB

    short8 ones;
#pragma unroll
    for (int i = 0; i < 8; i++) ones[i] = (short)0x3F80;  // bf16 1.0

    // staging: each of 4 waves stages 2 K-chunks + 2 V-chunks (1 KB each)
    const int rr  = lane >> 3;                 // 0..7
    const int swz = ((lane & 7) ^ rr) * 8;     // XOR-swizzled col offset (u16)
    auto stage = [&](int buf, int tt) {
        const int k0s = tt * 64;
        async_cp16(Kh + (size_t)(k0s + w * 8 + rr) * HDIM + swz,       &Ks[buf][w * 512]);
        async_cp16(Kh + (size_t)(k0s + (w + 4) * 8 + rr) * HDIM + swz, &Ks[buf][(w + 4) * 512]);
        async_cp16(Vh + (size_t)(w * 8 + rr) * SEQQ + k0s + swz,       &Vs[buf][w * 512]);
        async_cp16(Vh + (size_t)((w + 4) * 8 + rr) * SEQQ + k0s + swz, &Vs[buf][(w + 4) * 512]);
    };

    const int s7  = l15 & 7;
    const int sw1 = ((quad)     ^ s7) * 8;     // K dims chunk 0..31
    const int sw2 = ((quad + 4) ^ s7) * 8;     // K dims chunk 32..63
    // V b64 element offsets for permuted PV k-slots (chunk*8 + (quad&1)*4):
    const int vo0 = (((quad >> 1)    ) ^ s7) * 8 + (quad & 1) * 4;  // keys  4*quad..
    const int vo1 = (((quad >> 1) + 2) ^ s7) * 8 + (quad & 1) * 4;  // keys 16+4*quad..
    const int vo2 = (((quad >> 1) + 4) ^ s7) * 8 + (quad & 1) * 4;  // keys 32+4*quad..
    const int vo3 = (((quad >> 1) + 6) ^ s7) * 8 + (quad & 1) * 4;  // keys 48+4*quad..

    const int q0w   = qsub * 64 + w * 16;      // this wave's 16 q-rows
    const int tmaxp = qsub;                    // diag tile, same for all 4 waves

    // Q fragment loads FIRST (drained together with stage(0) by first vmcnt(0))
    short8 qf[2];
#pragma unroll
    for (int kk = 0; kk < 2; kk++)
        qf[kk] = load8(&Qh[(size_t)(q0w + l15) * HDIM + kk * 32 + quad * 8]);

    floatx4 O[4];
    floatx4 l_acc = {0.f, 0.f, 0.f, 0.f};
#pragma unroll
    for (int c = 0; c < 4; c++) { floatx4 zz = {0.f, 0.f, 0.f, 0.f}; O[c] = zz; }

    stage(0, 0);

    for (int t = 0; t <= tmaxp; ++t) {
        // stage(t) (4 DMAs, issued one full tile-compute ago) must be complete
        asm volatile("s_waitcnt vmcnt(0)" ::: "memory");
        __builtin_amdgcn_s_barrier();
        if (t < tmaxp) stage((t + 1) & 1, t + 1);   // prefetch distance 1

        const u16* KsB = &Ks[t & 1][0];
        const u16* VsB = &Vs[t & 1][0];
        const int k0 = t * 64;

        // S^T[c]: rows = key_local (c*16 + quad*4 + r), cols = q (l15)
        floatx4 S[4];
        __builtin_amdgcn_s_setprio(1);
#pragma unroll
        for (int c = 0; c < 4; c++) {
            const int rowb = (c * 16 + l15) * 64;
            floatx4 zz = {0.f, 0.f, 0.f, 0.f};
            S[c] = __builtin_amdgcn_mfma_f32_16x16x32_bf16(load8(&KsB[rowb + sw1]), qf[0], zz,   0, 0, 0);
            S[c] = __builtin_amdgcn_mfma_f32_16x16x32_bf16(load8(&KsB[rowb + sw2]), qf[1], S[c], 0, 0, 0);
        }
        __builtin_amdgcn_s_setprio(0);

        if (t == tmaxp) {
            const int q = q0w + l15;
#pragma unroll
            for (int c = 0; c < 4; c++)
#pragma unroll
                for (int r = 0; r < 4; r++)
                    if (k0 + c * 16 + quad * 4 + r > q) S[c][r] = -1e30f;
        }

#pragma unroll
        for (int c = 0; c < 4; c++)
#pragma unroll
            for (int r = 0; r < 4; r++)
                S[c][r] = __builtin_amdgcn_exp2f(S[c][r]);

        // ---- pack P into PV A-fragments (lane-local, permuted k-slots) ----
        union { short8 v; unsigned u[4]; } pf0, pf1;
        pf0.u[0] = pack2(S[0][0], S[0][1]);
        pf0.u[1] = pack2(S[0][2], S[0][3]);
        pf0.u[2] = pack2(S[1][0], S[1][1]);
        pf0.u[3] = pack2(S[1][2], S[1][3]);
        pf1.u[0] = pack2(S[2][0], S[2][1]);
        pf1.u[1] = pack2(S[2][2], S[2][3]);
        pf1.u[2] = pack2(S[3][0], S[3][1]);
        pf1.u[3] = pack2(S[3][2], S[3][3]);

        __builtin_amdgcn_s_setprio(1);
        l_acc = __builtin_amdgcn_mfma_f32_16x16x32_bf16(pf0.v, ones, l_acc, 0, 0, 0);
        l_acc = __builtin_amdgcn_mfma_f32_16x16x32_bf16(pf1.v, ones, l_acc, 0, 0, 0);

#pragma unroll
        for (int c2 = 0; c2 < 4; c2++) {
            const int rowb = (c2 * 16 + l15) * 64;
            bf16x4 a0 = load4v(&VsB[rowb + vo0]);
            bf16x4 a1 = load4v(&VsB[rowb + vo1]);
            bf16x4 a2 = load4v(&VsB[rowb + vo2]);
            bf16x4 a3 = load4v(&VsB[rowb + vo3]);
            short8 v0 = __builtin_shufflevector(a0, a1, 0, 1, 2, 3, 4, 5, 6, 7);
            short8 v1 = __builtin_shufflevector(a2, a3, 0, 1, 2, 3, 4, 5, 6, 7);
            O[c2] = __builtin_amdgcn_mfma_f32_16x16x32_bf16(pf0.v, v0, O[c2], 0, 0, 0);
            O[c2] = __builtin_amdgcn_mfma_f32_16x16x32_bf16(pf1.v, v1, O[c2], 0, 0, 0);
        }
        __builtin_amdgcn_s_setprio(0);
    }

    float inv_l[4];
#pragma unroll
    for (int r = 0; r < 4; r++) inv_l[r] = 1.0f / l_acc[r];

#pragma unroll
    for (int c2 = 0; c2 < 4; c2++)
#pragma unroll
        for (int r = 0; r < 4; r++) {
            const int q    = q0w + quad * 4 + r;
            const int colo = h * HDIM + c2 * 16 + l15;
            Out[(size_t)(b * SEQQ + q) * D_MODEL + colo] = f2b(O[c2][r] * inv_l[r]);
        }
}

// ---------------- o-proj GEMM: 64x64 tile, 1024 blocks (unchanged) ----------------
__global__ __launch_bounds__(256) void gemm_o(
    const u16* __restrict__ A, const u16* __restrict__ Bt, float* __restrict__ C)
{
    const int K = D_MODEL, N = D_MODEL;
    __shared__ __attribute__((aligned(16))) u16 As[3][64 * 32];
    __shared__ __attribute__((aligned(16))) u16 Bs[3][64 * 32];

    const int tid  = threadIdx.x;
    const int w    = tid >> 6;
    const int lane = tid & 63;
    const int l15  = lane & 15;
    const int quad = lane >> 4;
    const int wm   = w >> 1, wn = w & 1;
    const int tm   = blockIdx.x * 64, tn = blockIdx.y * 64;

    floatx4 acc[2][2];
#pragma unroll
    for (int i = 0; i < 2; i++)
#pragma unroll
        for (int j = 0; j < 2; j++) {
            floatx4 z = {0.f, 0.f, 0.f, 0.f};
            acc[i][j] = z;
        }

    const int srow = lane >> 2;
    const int scol = (lane & 3) * 8;

    auto stage = [&](int buf, int k0) {
        async_cp16(A  + (size_t)(tm + w * 16 + srow) * K + k0 + scol, &As[buf][w * 512]);
        async_cp16(Bt + (size_t)(tn + w * 16 + srow) * K + k0 + scol, &Bs[buf][w * 512]);
    };

    stage(0, 0);
    stage(1, 32);

    for (int kt = 0; kt < 32; ++kt) {
        if (kt < 30) asm volatile("s_waitcnt vmcnt(2)" ::: "memory");
        else         asm volatile("s_waitcnt vmcnt(0)" ::: "memory");
        __builtin_amdgcn_s_barrier();
        if (kt < 30) stage((kt + 2) % 3, (kt + 2) * 32);

        const u16* AsB = &As[kt % 3][0];
        const u16* BsB = &Bs[kt % 3][0];

        short8 af[2], bfr[2];
#pragma unroll
        for (int mi = 0; mi < 2; mi++)
            af[mi] = load8(&AsB[(wm * 32 + mi * 16 + l15) * 32 + quad * 8]);
#pragma unroll
        for (int ni = 0; ni < 2; ni++)
            bfr[ni] = load8(&BsB[(wn * 32 + ni * 16 + l15) * 32 + quad * 8]);
#pragma unroll
        for (int mi = 0; mi < 2; mi++)
#pragma unroll
            for (int ni = 0; ni < 2; ni++)
                acc[mi][ni] = __builtin_amdgcn_mfma_f32_16x16x32_bf16(af[mi], bfr[ni], acc[mi][ni], 0, 0, 0);
    }

#pragma unroll
    for (int mi = 0; mi < 2; mi++)
#pragma unroll
        for (int ni = 0; ni < 2; ni++)
#pragma unroll
            for (int rg = 0; rg < 4; rg++) {
                int row = tm + wm * 32 + mi * 16 + quad * 4 + rg;
                int col = tn + wn * 32 + ni * 16 + l15;
                C[(size_t)row * N + col] = acc[mi][ni][rg];
            }
}

// ---------------- launch ----------------
extern "C" void kernel_launch(void* const* d_in, const int* in_sizes, int n_in,
                              void* d_out, int out_size, void* d_ws, size_t ws_size,
                              hipStream_t stream)
{
    const float* X  = (const float*)d_in[0];
    const float* Wq = (const float*)d_in[1];
    const float* Wk = (const float*)d_in[2];
    const float* Wv = (const float*)d_in[3];
    const float* Wo = (const float*)d_in[4];
    const int* tpos = (const int*)d_in[5];
    float* out = (float*)d_out;
    char* ws = (char*)d_ws;

    const size_t MB = (size_t)1 << 20;
    u16*    Xb  = (u16*)(ws + 0);        // 8 MB bf16 X
    u16*    WqB = (u16*)(ws + 8 * MB);
    u16*    WkB = (u16*)(ws + 10 * MB);
    u16*    WvB = (u16*)(ws + 12 * MB);
    u16*    WoB = (u16*)(ws + 14 * MB);
    float2* tab = (float2*)(ws + 16 * MB);  // 512 KB rope table (j-major)
    u16*    Qt  = (u16*)(ws + 24 * MB);
    u16*    Kt  = (u16*)(ws + 32 * MB);
    u16*    Vt  = (u16*)(ws + 40 * MB);
    u16*   AOut = (u16*)(ws + 48 * MB);

    cvt_all<<<dim3(1024, 9), 256, 0, stream>>>(X, Wq, Wk, Wv, Wo, tpos,
                                               Xb, WqB, WkB, WvB, WoB, tab);

    gemm_qkv<<<dim3(64, 8), 256, 0, stream>>>(Xb, WqB, WkB, WvB,
                                              Qt, Kt, Vt, tab);
    attn_kernel<<<dim3(1024, 1, 1), 256, 0, stream>>>(Qt, Kt, Vt, AOut);
    gemm_o<<<dim3(64, 16), 256, 0, stream>>>(AOut, WoB, out);
}